// Round 4
// baseline (611.984 us; speedup 1.0000x reference)
//
#include <hip/hip_runtime.h>
#include <stdint.h>

#define N_KEYS 200000
#define N_Q    1024
#define DIM    128
#define KNN    50
#define DELTA  1e-3f

#define NKP     200064                 // 1563 * 128 padded keys
#define KTILES2 1563
#define NSTRIP  64
#define STRIP_L 24                     // 1563 = 27*25 + 37*24
#define STRIP_R 27
#define SAMPLES        2048
#define SAMPLE_STRIDE  97
#define SAMPLE_RANK    8
#define CAP_NEW 3072
#define MARGIN  0.25f                  // exact-recompute window slack
#define TSLACK  0.25f                  // tau filter slack for fp16 approx error

typedef __attribute__((ext_vector_type(8))) _Float16 f16x8;
typedef __attribute__((ext_vector_type(4))) float f32x4;
typedef unsigned long long ull;

#define GLD16(gsrc, ldst) __builtin_amdgcn_global_load_lds( \
    (const __attribute__((address_space(1))) unsigned int*)(gsrc), \
    (__attribute__((address_space(3))) unsigned int*)(ldst), 16, 0, 0)

// ================================================================ zero cnt
__global__ void zero_cnt_kernel(unsigned int* cnt) {
    int i = blockIdx.x * 256 + threadIdx.x;
    if (i < N_Q) cnt[i] = 0u;
}

// ================================================================ prep: fp32 -> f16 fragment-tiled + row sq-sums
__global__ void prep_kernel(const float* __restrict__ qry, const float* __restrict__ keys,
                            ushort* __restrict__ Kf, ushort* __restrict__ Qf,
                            float* __restrict__ ksq, float* __restrict__ qsq) {
    const int wave = threadIdx.x >> 6, lane = threadIdx.x & 63;
    const long NKG = NKP / 16;              // 12504
    const long NQG = N_Q / 16;              // 64
    const long grp = (long)blockIdx.x * 4 + wave;
    if (grp >= NKG + NQG) return;
    const bool isq = (grp >= NKG);
    const long lgrp = isq ? (grp - NKG) : grp;
    const long row = lgrp * 16 + (lane & 15);
    const int  hi  = lane >> 4;
    const bool valid = isq || (row < N_KEYS);
    const float* src = isq ? (qry + row * DIM) : (keys + (valid ? row * DIM : 0));

    float ss = 0.f;
    uint4 hv[4];
    #pragma unroll
    for (int s = 0; s < 4; ++s) {
        float4 a, b;
        if (valid) {
            const float4* p = (const float4*)(src + s * 32 + hi * 8);
            a = p[0]; b = p[1];
        } else {
            a = make_float4(0.f, 0.f, 0.f, 0.f); b = a;
        }
        ss = fmaf(a.x, a.x, ss); ss = fmaf(a.y, a.y, ss);
        ss = fmaf(a.z, a.z, ss); ss = fmaf(a.w, a.w, ss);
        ss = fmaf(b.x, b.x, ss); ss = fmaf(b.y, b.y, ss);
        ss = fmaf(b.z, b.z, ss); ss = fmaf(b.w, b.w, ss);
        const float v[8] = {a.x, a.y, a.z, a.w, b.x, b.y, b.z, b.w};
        unsigned h[8];
        #pragma unroll
        for (int j = 0; j < 8; ++j) {
            _Float16 t = (_Float16)v[j];
            h[j] = (unsigned)__builtin_bit_cast(unsigned short, t);
        }
        hv[s].x = h[0] | (h[1] << 16); hv[s].y = h[2] | (h[3] << 16);
        hv[s].z = h[4] | (h[5] << 16); hv[s].w = h[6] | (h[7] << 16);
    }
    ss += __shfl_xor(ss, 16);
    ss += __shfl_xor(ss, 32);

    ushort* dst = isq ? Qf : Kf;
    #pragma unroll
    for (int s = 0; s < 4; ++s)
        *(uint4*)(dst + (size_t)(lgrp * 4 + s) * 512 + lane * 8) = hv[s];

    if (lane < 16) {
        if (isq) qsq[row] = ss;
        else if (row < NKP) ksq[row] = valid ? ss : 3.0e38f;
    }
}

// ================================================================ gather sampled rows -> compact buffer (1 MB)
__global__ void gather_kernel(const float* __restrict__ keys, float* __restrict__ Sc) {
    int f = blockIdx.x * 512 + threadIdx.x;
    #pragma unroll
    for (int p = 0; p < 2; ++p, f += 256) {
        const int row = f >> 5, c4 = f & 31;
        ((float4*)Sc)[f] = ((const float4*)(keys + (size_t)row * SAMPLE_STRIDE * DIM))[c4];
    }
}

// ================================================================ per-query sampled threshold, 4 queries/block
__global__ void tau_kernel(const float* __restrict__ qry, const float* __restrict__ Sc,
                           float* __restrict__ tau0, int rank) {
    __shared__ float Qs[4][DIM];        // 2 KB
    __shared__ float Ds[4][SAMPLES];    // 32 KB
    const int q0 = blockIdx.x * 4, tid = threadIdx.x;
    if (tid < 128) ((float4*)&Qs[0][0])[tid] = ((const float4*)(qry + (size_t)q0 * DIM))[tid];
    __syncthreads();

    const int sub = tid & 15, grp = tid >> 4;
    for (int s = grp; s < SAMPLES; s += 16) {
        const float4* kr = (const float4*)(Sc + (size_t)s * DIM);
        const float4 a = kr[sub * 2], b = kr[sub * 2 + 1];
        #pragma unroll
        for (int qi = 0; qi < 4; ++qi) {
            const float4 qa = ((float4*)&Qs[qi][0])[sub * 2];
            const float4 qb = ((float4*)&Qs[qi][0])[sub * 2 + 1];
            float t, acc;
            t = qa.x - a.x; acc = t * t;
            t = qa.y - a.y; acc = fmaf(t, t, acc);
            t = qa.z - a.z; acc = fmaf(t, t, acc);
            t = qa.w - a.w; acc = fmaf(t, t, acc);
            t = qb.x - b.x; acc = fmaf(t, t, acc);
            t = qb.y - b.y; acc = fmaf(t, t, acc);
            t = qb.z - b.z; acc = fmaf(t, t, acc);
            t = qb.w - b.w; acc = fmaf(t, t, acc);
            #pragma unroll
            for (int m = 1; m < 16; m <<= 1) acc += __shfl_xor(acc, m);
            if (sub == 0) Ds[qi][s] = acc;
        }
    }
    __syncthreads();

    // radix-select per wave (wave w -> query q0+w), no barriers needed
    const int wave = tid >> 6, lane = tid & 63;
    const float* D = Ds[wave];
    unsigned int v = 0;
    for (int bit = 30; bit >= 0; bit--) {
        const unsigned int tbits = v | (1u << bit);
        const float tf = __uint_as_float(tbits);
        unsigned int lc = 0;
        for (int i = lane; i < SAMPLES; i += 64) lc += (D[i] < tf) ? 1u : 0u;
        #pragma unroll
        for (int m = 1; m < 64; m <<= 1) lc += __shfl_xor(lc, m);
        if (lc < (unsigned)rank) v = tbits;
    }
    if (lane == 0) tau0[q0 + wave] = __uint_as_float(v);
}

// ================================================================ f16 MFMA distance GEMM + filter (K-strip, dbuf LDS, reg Q)
__global__ __launch_bounds__(256, 2)
void mfma_filter_kernel(const ushort* __restrict__ Qf, const ushort* __restrict__ Kf,
                        const float* __restrict__ ksq_g, const float* __restrict__ qsq_g,
                        const float* __restrict__ tau_g,
                        unsigned int* __restrict__ cnt, float2* __restrict__ cand, int cap) {
    __shared__ ushort Blds[2][16384];   // 2 x 32 KB K-tile double buffer

    // blockIdx = qt*64 + strip -> 8 strip-sharing blocks land on same XCD (round-robin)
    const int wg = blockIdx.x;
    const int qt = wg >> 6;
    const int strip = wg & 63;
    int t0, len;
    if (strip < STRIP_R) { t0 = strip * (STRIP_L + 1); len = STRIP_L + 1; }
    else { t0 = STRIP_R * (STRIP_L + 1) + (strip - STRIP_R) * STRIP_L; len = STRIP_L; }

    const int qbase = qt * 128;
    const int tid = threadIdx.x, lane = tid & 63, wave = tid >> 6;
    const int wr = wave >> 1, wc = wave & 1;
    const int col = lane & 15, rowb = (lane >> 4) * 4;

    // Q fragments -> registers (coalesced 16B loads, fragment-ordered global)
    f16x8 af[4][4];   // [row-frag i][k-step s]
    {
        const ushort* qsrc = Qf + (size_t)qt * 16384 + lane * 8;
        #pragma unroll
        for (int i = 0; i < 4; ++i)
            #pragma unroll
            for (int s = 0; s < 4; ++s)
                af[i][s] = *(const f16x8*)(qsrc + ((wr * 4 + i) * 4 + s) * 512);
    }
    // per-lane thresholds (loop-invariant over the whole strip)
    float thr_r[4][4], qsq_r[4][4];
    #pragma unroll
    for (int i = 0; i < 4; ++i)
        #pragma unroll
        for (int r = 0; r < 4; ++r) {
            const int qg = qbase + wr * 64 + i * 16 + rowb + r;
            const float qs = qsq_g[qg];
            qsq_r[i][r] = qs;
            thr_r[i][r] = tau_g[qg] + TSLACK - qs;
        }

    // prologue: stage first K tile into buf 0
    {
        const ushort* src = Kf + (size_t)t0 * 16384 + lane * 8;
        #pragma unroll
        for (int c = 0; c < 8; ++c)
            GLD16(src + (wave * 8 + c) * 512, &Blds[0][(wave * 8 + c) * 512]);
    }
    __syncthreads();   // compiler emits vmcnt(0) drain here

    for (int t = 0; t < len; ++t) {
        const int kt = t0 + t;
        const int cur = t & 1;

        // per-tile ksq (L2-hot; issued early to hide latency)
        float ksq4[4];
        #pragma unroll
        for (int j = 0; j < 4; ++j)
            ksq4[j] = ksq_g[kt * 128 + wc * 64 + j * 16 + col];

        // issue next-tile stage BEFORE consuming current (T3 2-phase)
        if (t + 1 < len) {
            const ushort* src = Kf + (size_t)(kt + 1) * 16384 + lane * 8;
            #pragma unroll
            for (int c = 0; c < 8; ++c)
                GLD16(src + (wave * 8 + c) * 512, &Blds[cur ^ 1][(wave * 8 + c) * 512]);
        }

        // compute current tile: 16 ds_read_b128 + 64 MFMA per wave
        f32x4 acc[4][4];
        #pragma unroll
        for (int i = 0; i < 4; ++i)
            #pragma unroll
            for (int j = 0; j < 4; ++j) acc[i][j] = (f32x4){0.f, 0.f, 0.f, 0.f};

        #pragma unroll
        for (int s = 0; s < 4; ++s) {
            f16x8 bfr[4];
            #pragma unroll
            for (int j = 0; j < 4; ++j)
                bfr[j] = *(const f16x8*)&Blds[cur][((wc * 4 + j) * 4 + s) * 512 + lane * 8];
            #pragma unroll
            for (int i = 0; i < 4; ++i)
                #pragma unroll
                for (int j = 0; j < 4; ++j)
                    acc[i][j] = __builtin_amdgcn_mfma_f32_16x16x32_f16(af[i][s], bfr[j], acc[i][j], 0, 0, 0);
        }

        // filter epilogue
        #pragma unroll
        for (int i = 0; i < 4; ++i) {
            #pragma unroll
            for (int j = 0; j < 4; ++j) {
                #pragma unroll
                for (int r = 0; r < 4; ++r) {
                    const float mm = fmaf(-2.f, acc[i][j][r], ksq4[j]);
                    if (mm < thr_r[i][r]) {
                        const int qg = qbase + wr * 64 + i * 16 + rowb + r;
                        const float dist = qsq_r[i][r] + mm;
                        const unsigned p = atomicAdd(&cnt[qg], 1u);
                        if ((int)p < cap)
                            cand[(size_t)qg * cap + p] = make_float2(dist,
                                __uint_as_float((unsigned)(kt * 128 + wc * 64 + j * 16 + col)));
                    }
                }
            }
        }
        __syncthreads();   // drains next-tile stage (vmcnt(0)) + protects buffer reuse
    }
}

// ================================================================ select: approx window -> exact fp32 recompute -> IDW
__global__ void select_exact_kernel(const float2* __restrict__ cand, const unsigned int* __restrict__ cnt,
                                    const float* __restrict__ keys, const float* __restrict__ qry,
                                    const float* __restrict__ ksq_g, const float* __restrict__ qsq_g,
                                    const float* __restrict__ values, float* __restrict__ out, int cap) {
    __shared__ float Qs[DIM];
    __shared__ ull keyarr[CAP_NEW];
    __shared__ int keep[256];
    __shared__ ull ex[256];
    __shared__ ull sel[KNN];
    __shared__ float vv[KNN];
    __shared__ unsigned int cnt_s, ns;
    const int q = blockIdx.x, tid = threadIdx.x;

    if (tid < 32) ((float4*)Qs)[tid] = ((const float4*)(qry + (size_t)q * DIM))[tid];
    const int c = min((int)cnt[q], cap);
    for (int i = tid; i < c; i += 256) {
        const float2 f = cand[(size_t)q * cap + i];
        keyarr[i] = ((ull)__float_as_uint(f.x) << 32) | __float_as_uint(f.y);
    }
    __syncthreads();

    const int ksel = min(KNN, c);
    if (ksel == 0) { if (tid == 0) out[q] = 0.f; return; }

    // 1) ksel-th smallest approx key
    ull lo = 0ull, hi = ~0ull;
    while (hi - lo > 1ull) {
        const ull mid = lo + ((hi - lo) >> 1);
        if (tid == 0) cnt_s = 0;
        __syncthreads();
        unsigned int lc = 0;
        for (int i = tid; i < c; i += 256) lc += (keyarr[i] < mid) ? 1u : 0u;
        #pragma unroll
        for (int off = 32; off; off >>= 1) lc += __shfl_down(lc, off);
        if ((tid & 63) == 0) atomicAdd(&cnt_s, lc);
        __syncthreads();
        if (cnt_s >= (unsigned)ksel) hi = mid; else lo = mid;
        __syncthreads();
    }
    const float a50 = __uint_as_float((unsigned)(lo >> 32));
    const unsigned cutb = __float_as_uint(a50 + MARGIN);

    // 2) keep approx <= a50 + margin
    if (tid == 0) ns = 0;
    __syncthreads();
    for (int i = tid; i < c; i += 256) {
        if ((unsigned)(keyarr[i] >> 32) <= cutb) {
            const unsigned p = atomicAdd(&ns, 1u);
            if (p < 256u) keep[p] = (int)(keyarr[i] & 0xFFFFFFFFull);
        }
    }
    __syncthreads();
    const int m = min((int)ns, 256);

    // 3) exact fp32 distances for kept window
    const float qsq = qsq_g[q];
    for (int j = tid; j < m; j += 256) {
        const int kidx = keep[j];
        const float* kr = keys + (size_t)kidx * DIM;
        float dot = 0.f;
        for (int d = 0; d < DIM; d++) dot = fmaf(Qs[d], kr[d], dot);
        const float mm = fmaf(-2.f, dot, ksq_g[kidx]);
        const float dist = qsq + mm;
        ex[j] = ((ull)__float_as_uint(dist) << 32) | (unsigned)kidx;
    }
    __syncthreads();

    const int kex = min(KNN, m);
    // 4) exact kex-th smallest among kept
    lo = 0ull; hi = ~0ull;
    while (hi - lo > 1ull) {
        const ull mid = lo + ((hi - lo) >> 1);
        if (tid == 0) cnt_s = 0;
        __syncthreads();
        unsigned int lc = 0;
        for (int i = tid; i < m; i += 256) lc += (ex[i] < mid) ? 1u : 0u;
        #pragma unroll
        for (int off = 32; off; off >>= 1) lc += __shfl_down(lc, off);
        if ((tid & 63) == 0) atomicAdd(&cnt_s, lc);
        __syncthreads();
        if (cnt_s >= (unsigned)kex) hi = mid; else lo = mid;
        __syncthreads();
    }
    const ull thr2 = lo;

    if (tid == 0) ns = 0;
    __syncthreads();
    for (int i = tid; i < m; i += 256) {
        if (ex[i] <= thr2) {
            const unsigned p = atomicAdd(&ns, 1u);
            if (p < (unsigned)KNN) sel[p] = ex[i];
        }
    }
    __syncthreads();

    if (tid == 0) {  // deterministic: insertion sort ascending (dist, idx)
        for (int a = 1; a < kex; a++) {
            const ull xk = sel[a];
            int b = a - 1;
            while (b >= 0 && sel[b] > xk) { sel[b + 1] = sel[b]; b--; }
            sel[b + 1] = xk;
        }
    }
    __syncthreads();
    if (tid < kex) vv[tid] = values[(unsigned)(sel[tid] & 0xFFFFFFFFull)];
    __syncthreads();

    if (tid == 0) {
        const float d0 = fmaxf(__uint_as_float((unsigned)(sel[0] >> 32)), 0.f);
        float res;
        if (d0 == 0.f) {
            res = vv[0];
        } else {
            float S = 0.f;
            for (int i = 0; i < kex; i++) {
                const float di = fmaxf(__uint_as_float((unsigned)(sel[i] >> 32)), 0.f);
                S += 1.f / (di + DELTA);
            }
            float o = 0.f;
            for (int i = 0; i < kex; i++) {
                const float di = fmaxf(__uint_as_float((unsigned)(sel[i] >> 32)), 0.f);
                const float w = 1.f / (di + DELTA);
                o += (w / S) * vv[i];
            }
            res = o;
        }
        out[q] = res;
    }
}

// ================================================================ launcher
extern "C" void kernel_launch(void* const* d_in, const int* in_sizes, int n_in,
                              void* d_out, int out_size, void* d_ws, size_t ws_size,
                              hipStream_t stream) {
    const float* qry    = (const float*)d_in[0];   // [1024,128]
    const float* keys   = (const float*)d_in[1];   // [200000,128]
    const float* values = (const float*)d_in[2];   // [200000,1]
    float* out = (float*)d_out;
    char* ws = (char*)d_ws;

    const size_t KF_OFF   = 0;
    const size_t QF_OFF   = KF_OFF + (size_t)NKP * DIM * 2;       // 51,216,384
    const size_t KSQ_OFF  = QF_OFF + (size_t)N_Q * DIM * 2;
    const size_t QSQ_OFF  = KSQ_OFF + (size_t)NKP * 4;
    const size_t TAU_OFF  = QSQ_OFF + 4096;
    const size_t CNT_OFF  = TAU_OFF + 4096;
    const size_t SC_OFF   = CNT_OFF + 4096;
    const size_t CAND_OFF = SC_OFF + (size_t)SAMPLES * DIM * 4;

    ushort* Kf  = (ushort*)(ws + KF_OFF);
    ushort* Qf  = (ushort*)(ws + QF_OFF);
    float*  ksq = (float*)(ws + KSQ_OFF);
    float*  qsq = (float*)(ws + QSQ_OFF);
    float*  tau = (float*)(ws + TAU_OFF);
    unsigned int* cnt = (unsigned int*)(ws + CNT_OFF);
    float*  Sc  = (float*)(ws + SC_OFF);
    float2* cand = (float2*)(ws + CAND_OFF);

    const int PREP_BLOCKS = (int)((NKP / 16 + N_Q / 16 + 3) / 4);   // 3142

    hipLaunchKernelGGL(zero_cnt_kernel, dim3(4), dim3(256), 0, stream, cnt);
    hipLaunchKernelGGL(gather_kernel, dim3(128), dim3(256), 0, stream, keys, Sc);
    hipLaunchKernelGGL(tau_kernel, dim3(N_Q / 4), dim3(256), 0, stream, qry, Sc, tau, SAMPLE_RANK);
    hipLaunchKernelGGL(prep_kernel, dim3(PREP_BLOCKS), dim3(256), 0, stream,
                       qry, keys, Kf, Qf, ksq, qsq);
    hipLaunchKernelGGL(mfma_filter_kernel, dim3(8 * NSTRIP), dim3(256), 0, stream,
                       Qf, Kf, ksq, qsq, tau, cnt, cand, CAP_NEW);
    hipLaunchKernelGGL(select_exact_kernel, dim3(N_Q), dim3(256), 0, stream,
                       cand, cnt, keys, qry, ksq, qsq, values, out, CAP_NEW);
}

// Round 5
// 429.014 us; speedup vs baseline: 1.4265x; 1.4265x over previous
//
#include <hip/hip_runtime.h>
#include <stdint.h>

#define N_KEYS 200000
#define N_Q    1024
#define DIM    128
#define KNN    50
#define DELTA  1e-3f

#define NKP     200064                 // 1563 * 128 padded keys
#define KTILES2 1563
#define NSTRIP  64
#define STRIP_L 24                     // 1563 = 27*25 + 37*24
#define STRIP_R 27
#define SAMPLES        2048
#define SAMPLE_STRIDE  97
#define SAMPLE_RANK    8
#define CAP_NEW 3072
#define SEG     64                     // per (strip,query) candidate slots
#define OVFCAP  65536
#define MARGIN  0.25f
#define TSLACK  0.25f

typedef __attribute__((ext_vector_type(8))) _Float16 f16x8;
typedef __attribute__((ext_vector_type(4))) float f32x4;
typedef unsigned long long ull;

#define GLD16(gsrc, ldst) __builtin_amdgcn_global_load_lds( \
    (const __attribute__((address_space(1))) unsigned int*)(gsrc), \
    (__attribute__((address_space(3))) unsigned int*)(ldst), 16, 0, 0)

// ================================================================ prep: fp32 -> f16 fragment-tiled + row sq-sums
__global__ void prep_kernel(const float* __restrict__ qry, const float* __restrict__ keys,
                            ushort* __restrict__ Kf, ushort* __restrict__ Qf,
                            float* __restrict__ ksq, float* __restrict__ qsq) {
    const int wave = threadIdx.x >> 6, lane = threadIdx.x & 63;
    const long NKG = NKP / 16;              // 12504
    const long NQG = N_Q / 16;              // 64
    const long grp = (long)blockIdx.x * 4 + wave;
    if (grp >= NKG + NQG) return;
    const bool isq = (grp >= NKG);
    const long lgrp = isq ? (grp - NKG) : grp;
    const long row = lgrp * 16 + (lane & 15);
    const int  hi  = lane >> 4;
    const bool valid = isq || (row < N_KEYS);
    const float* src = isq ? (qry + row * DIM) : (keys + (valid ? row * DIM : 0));

    float ss = 0.f;
    uint4 hv[4];
    #pragma unroll
    for (int s = 0; s < 4; ++s) {
        float4 a, b;
        if (valid) {
            const float4* p = (const float4*)(src + s * 32 + hi * 8);
            a = p[0]; b = p[1];
        } else {
            a = make_float4(0.f, 0.f, 0.f, 0.f); b = a;
        }
        ss = fmaf(a.x, a.x, ss); ss = fmaf(a.y, a.y, ss);
        ss = fmaf(a.z, a.z, ss); ss = fmaf(a.w, a.w, ss);
        ss = fmaf(b.x, b.x, ss); ss = fmaf(b.y, b.y, ss);
        ss = fmaf(b.z, b.z, ss); ss = fmaf(b.w, b.w, ss);
        const float v[8] = {a.x, a.y, a.z, a.w, b.x, b.y, b.z, b.w};
        unsigned h[8];
        #pragma unroll
        for (int j = 0; j < 8; ++j) {
            _Float16 t = (_Float16)v[j];
            h[j] = (unsigned)__builtin_bit_cast(unsigned short, t);
        }
        hv[s].x = h[0] | (h[1] << 16); hv[s].y = h[2] | (h[3] << 16);
        hv[s].z = h[4] | (h[5] << 16); hv[s].w = h[6] | (h[7] << 16);
    }
    ss += __shfl_xor(ss, 16);
    ss += __shfl_xor(ss, 32);

    ushort* dst = isq ? Qf : Kf;
    #pragma unroll
    for (int s = 0; s < 4; ++s)
        *(uint4*)(dst + (size_t)(lgrp * 4 + s) * 512 + lane * 8) = hv[s];

    if (lane < 16) {
        if (isq) qsq[row] = ss;
        else if (row < NKP) ksq[row] = valid ? ss : 3.0e38f;
    }
}

// ================================================================ gather sampled rows -> compact buffer (+ ovf_cnt init)
__global__ void gather_kernel(const float* __restrict__ keys, float* __restrict__ Sc,
                              unsigned int* __restrict__ ovf_cnt) {
    if (blockIdx.x == 0 && threadIdx.x == 0) *ovf_cnt = 0u;
    int f = blockIdx.x * 512 + threadIdx.x;
    #pragma unroll
    for (int p = 0; p < 2; ++p, f += 256) {
        const int row = f >> 5, c4 = f & 31;
        ((float4*)Sc)[f] = ((const float4*)(keys + (size_t)row * SAMPLE_STRIDE * DIM))[c4];
    }
}

// ================================================================ per-query sampled threshold, 4 queries/block
__global__ void tau_kernel(const float* __restrict__ qry, const float* __restrict__ Sc,
                           float* __restrict__ tau0, int rank) {
    __shared__ float Qs[4][DIM];
    __shared__ float Ds[4][SAMPLES];
    const int q0 = blockIdx.x * 4, tid = threadIdx.x;
    if (tid < 128) ((float4*)&Qs[0][0])[tid] = ((const float4*)(qry + (size_t)q0 * DIM))[tid];
    __syncthreads();

    const int sub = tid & 15, grp = tid >> 4;
    for (int s = grp; s < SAMPLES; s += 16) {
        const float4* kr = (const float4*)(Sc + (size_t)s * DIM);
        const float4 a = kr[sub * 2], b = kr[sub * 2 + 1];
        #pragma unroll
        for (int qi = 0; qi < 4; ++qi) {
            const float4 qa = ((float4*)&Qs[qi][0])[sub * 2];
            const float4 qb = ((float4*)&Qs[qi][0])[sub * 2 + 1];
            float t, acc;
            t = qa.x - a.x; acc = t * t;
            t = qa.y - a.y; acc = fmaf(t, t, acc);
            t = qa.z - a.z; acc = fmaf(t, t, acc);
            t = qa.w - a.w; acc = fmaf(t, t, acc);
            t = qb.x - b.x; acc = fmaf(t, t, acc);
            t = qb.y - b.y; acc = fmaf(t, t, acc);
            t = qb.z - b.z; acc = fmaf(t, t, acc);
            t = qb.w - b.w; acc = fmaf(t, t, acc);
            #pragma unroll
            for (int m = 1; m < 16; m <<= 1) acc += __shfl_xor(acc, m);
            if (sub == 0) Ds[qi][s] = acc;
        }
    }
    __syncthreads();

    const int wave = tid >> 6, lane = tid & 63;
    const float* D = Ds[wave];
    unsigned int v = 0;
    for (int bit = 30; bit >= 0; bit--) {
        const unsigned int tbits = v | (1u << bit);
        const float tf = __uint_as_float(tbits);
        unsigned int lc = 0;
        for (int i = lane; i < SAMPLES; i += 64) lc += (D[i] < tf) ? 1u : 0u;
        #pragma unroll
        for (int m = 1; m < 64; m <<= 1) lc += __shfl_xor(lc, m);
        if (lc < (unsigned)rank) v = tbits;
    }
    if (lane == 0) tau0[q0 + wave] = __uint_as_float(v);
}

// ================================================================ f16 MFMA distance GEMM + filter
// Block-private candidate segments: one LDS atomic + one plain store per hit.
__global__ __launch_bounds__(256, 2)
void mfma_filter_kernel(const ushort* __restrict__ Qf, const ushort* __restrict__ Kf,
                        const float* __restrict__ ksq_g, const float* __restrict__ qsq_g,
                        const float* __restrict__ tau_g,
                        uint2* __restrict__ cand2, unsigned int* __restrict__ cnt2,
                        uint2* __restrict__ ovf, unsigned int* __restrict__ ovf_cnt) {
    __shared__ ushort Blds[2][16384];     // 2 x 32 KB K-tile double buffer
    __shared__ unsigned int lcnt[128];    // per-query local segment counts

    const int wg = blockIdx.x;
    const int qt = wg >> 6;
    const int strip = wg & 63;            // strip-sharing blocks: wg%8 == strip%8 -> same XCD
    int t0, len;
    if (strip < STRIP_R) { t0 = strip * (STRIP_L + 1); len = STRIP_L + 1; }
    else { t0 = STRIP_R * (STRIP_L + 1) + (strip - STRIP_R) * STRIP_L; len = STRIP_L; }

    const int qbase = qt * 128;
    const int tid = threadIdx.x, lane = tid & 63, wave = tid >> 6;
    const int wr = wave >> 1, wc = wave & 1;
    const int col = lane & 15, rowb = (lane >> 4) * 4;

    // Q fragments -> registers
    f16x8 af[4][4];
    {
        const ushort* qsrc = Qf + (size_t)qt * 16384 + lane * 8;
        #pragma unroll
        for (int i = 0; i < 4; ++i)
            #pragma unroll
            for (int s = 0; s < 4; ++s)
                af[i][s] = *(const f16x8*)(qsrc + ((wr * 4 + i) * 4 + s) * 512);
    }
    float thr_r[4][4], qsq_r[4][4];
    #pragma unroll
    for (int i = 0; i < 4; ++i)
        #pragma unroll
        for (int r = 0; r < 4; ++r) {
            const int qg = qbase + wr * 64 + i * 16 + rowb + r;
            const float qs = qsq_g[qg];
            qsq_r[i][r] = qs;
            thr_r[i][r] = tau_g[qg] + TSLACK - qs;
        }

    if (tid < 128) lcnt[tid] = 0u;
    {   // prologue stage -> buf 0
        const ushort* src = Kf + (size_t)t0 * 16384 + lane * 8;
        #pragma unroll
        for (int c = 0; c < 8; ++c)
            GLD16(src + (wave * 8 + c) * 512, &Blds[0][(wave * 8 + c) * 512]);
    }
    __syncthreads();

    for (int t = 0; t < len; ++t) {
        const int kt = t0 + t;
        const int cur = t & 1;

        float ksq4[4];
        #pragma unroll
        for (int j = 0; j < 4; ++j)
            ksq4[j] = ksq_g[kt * 128 + wc * 64 + j * 16 + col];

        if (t + 1 < len) {
            const ushort* src = Kf + (size_t)(kt + 1) * 16384 + lane * 8;
            #pragma unroll
            for (int c = 0; c < 8; ++c)
                GLD16(src + (wave * 8 + c) * 512, &Blds[cur ^ 1][(wave * 8 + c) * 512]);
        }

        f32x4 acc[4][4];
        #pragma unroll
        for (int i = 0; i < 4; ++i)
            #pragma unroll
            for (int j = 0; j < 4; ++j) acc[i][j] = (f32x4){0.f, 0.f, 0.f, 0.f};

        #pragma unroll
        for (int s = 0; s < 4; ++s) {
            f16x8 bfr[4];
            #pragma unroll
            for (int j = 0; j < 4; ++j)
                bfr[j] = *(const f16x8*)&Blds[cur][((wc * 4 + j) * 4 + s) * 512 + lane * 8];
            #pragma unroll
            for (int i = 0; i < 4; ++i)
                #pragma unroll
                for (int j = 0; j < 4; ++j)
                    acc[i][j] = __builtin_amdgcn_mfma_f32_16x16x32_f16(af[i][s], bfr[j], acc[i][j], 0, 0, 0);
        }

        // epilogue: LDS-slot append + fire-and-forget store (no global atomics)
        #pragma unroll
        for (int i = 0; i < 4; ++i) {
            #pragma unroll
            for (int j = 0; j < 4; ++j) {
                #pragma unroll
                for (int r = 0; r < 4; ++r) {
                    const float mm = fmaf(-2.f, acc[i][j][r], ksq4[j]);
                    if (mm < thr_r[i][r]) {
                        const int ql = wr * 64 + i * 16 + rowb + r;
                        const unsigned kg = (unsigned)(kt * 128 + wc * 64 + j * 16 + col);
                        const float dist = qsq_r[i][r] + mm;
                        const unsigned slot = atomicAdd(&lcnt[ql], 1u);
                        if (slot < (unsigned)SEG) {
                            cand2[((size_t)strip * N_Q + qbase + ql) * SEG + slot] =
                                make_uint2(__float_as_uint(dist), kg);
                        } else {
                            const unsigned op = atomicAdd(ovf_cnt, 1u);
                            if (op < (unsigned)OVFCAP)
                                ovf[op] = make_uint2(__float_as_uint(dist),
                                                     ((unsigned)(qbase + ql) << 18) | kg);
                        }
                    }
                }
            }
        }
        __syncthreads();
    }

    if (tid < 128) {
        const unsigned c = lcnt[tid];
        cnt2[(size_t)strip * N_Q + qbase + tid] = (c > (unsigned)SEG) ? (unsigned)SEG : c;
    }
}

// ================================================================ select: gather segments -> approx window -> exact fp32 -> IDW
__global__ void select_exact_kernel(const uint2* __restrict__ cand2, const unsigned int* __restrict__ cnt2,
                                    const uint2* __restrict__ ovf, const unsigned int* __restrict__ ovf_cnt,
                                    const float* __restrict__ keys, const float* __restrict__ qry,
                                    const float* __restrict__ ksq_g, const float* __restrict__ qsq_g,
                                    const float* __restrict__ values, float* __restrict__ out) {
    __shared__ float Qs[DIM];
    __shared__ ull keyarr[CAP_NEW];
    __shared__ unsigned offs[NSTRIP + 1];
    __shared__ int keep[256];
    __shared__ ull ex[256];
    __shared__ ull sel[KNN];
    __shared__ float vv[KNN];
    __shared__ unsigned int cnt_s, ns, ns_extra;
    const int q = blockIdx.x, tid = threadIdx.x;

    if (tid < 32) ((float4*)Qs)[tid] = ((const float4*)(qry + (size_t)q * DIM))[tid];
    if (tid == 0) ns_extra = 0;

    // segment prefix-scan (wave 0)
    if (tid < NSTRIP) {
        unsigned sc = cnt2[(size_t)tid * N_Q + q];
        #pragma unroll
        for (int d = 1; d < NSTRIP; d <<= 1) {
            unsigned n = __shfl_up(sc, d);
            if (tid >= d) sc += n;
        }
        offs[tid + 1] = sc;
        if (tid == 0) offs[0] = 0;
    }
    __syncthreads();

    // copy segments: 4 threads per strip
    {
        const int s = tid >> 2, sub = tid & 3;
        const unsigned o = offs[s], n = offs[s + 1] - o;
        const uint2* seg = cand2 + ((size_t)s * N_Q + q) * SEG;
        for (unsigned i = sub; i < n; i += 4) {
            const unsigned dsti = o + i;
            if (dsti < (unsigned)CAP_NEW) {
                const uint2 e = seg[i];
                keyarr[dsti] = ((ull)e.x << 32) | e.y;
            }
        }
    }
    // rare overflow entries
    {
        const unsigned no = min(*ovf_cnt, (unsigned)OVFCAP);
        for (unsigned i = tid; i < no; i += 256) {
            const uint2 e = ovf[i];
            if ((e.y >> 18) == (unsigned)q) {
                const unsigned p = atomicAdd(&ns_extra, 1u);
                const unsigned dsti = offs[NSTRIP] + p;
                if (dsti < (unsigned)CAP_NEW)
                    keyarr[dsti] = ((ull)e.x << 32) | (e.y & 0x3FFFFu);
            }
        }
    }
    __syncthreads();
    const int c = min((int)(offs[NSTRIP] + ns_extra), CAP_NEW);

    const int ksel = min(KNN, c);
    if (ksel == 0) { if (tid == 0) out[q] = 0.f; return; }

    // 1) ksel-th smallest approx key
    ull lo = 0ull, hi = ~0ull;
    while (hi - lo > 1ull) {
        const ull mid = lo + ((hi - lo) >> 1);
        if (tid == 0) cnt_s = 0;
        __syncthreads();
        unsigned int lc = 0;
        for (int i = tid; i < c; i += 256) lc += (keyarr[i] < mid) ? 1u : 0u;
        #pragma unroll
        for (int off = 32; off; off >>= 1) lc += __shfl_down(lc, off);
        if ((tid & 63) == 0) atomicAdd(&cnt_s, lc);
        __syncthreads();
        if (cnt_s >= (unsigned)ksel) hi = mid; else lo = mid;
        __syncthreads();
    }
    const float a50 = __uint_as_float((unsigned)(lo >> 32));
    const unsigned cutb = __float_as_uint(a50 + MARGIN);

    // 2) keep approx <= a50 + margin
    if (tid == 0) ns = 0;
    __syncthreads();
    for (int i = tid; i < c; i += 256) {
        if ((unsigned)(keyarr[i] >> 32) <= cutb) {
            const unsigned p = atomicAdd(&ns, 1u);
            if (p < 256u) keep[p] = (int)(keyarr[i] & 0xFFFFFFFFull);
        }
    }
    __syncthreads();
    const int m = min((int)ns, 256);

    // 3) exact fp32 distances for kept window
    const float qsq = qsq_g[q];
    for (int j = tid; j < m; j += 256) {
        const int kidx = keep[j];
        const float* kr = keys + (size_t)kidx * DIM;
        float dot = 0.f;
        for (int d = 0; d < DIM; d++) dot = fmaf(Qs[d], kr[d], dot);
        const float mm = fmaf(-2.f, dot, ksq_g[kidx]);
        const float dist = qsq + mm;
        ex[j] = ((ull)__float_as_uint(dist) << 32) | (unsigned)kidx;
    }
    __syncthreads();

    const int kex = min(KNN, m);
    // 4) exact kex-th smallest among kept
    lo = 0ull; hi = ~0ull;
    while (hi - lo > 1ull) {
        const ull mid = lo + ((hi - lo) >> 1);
        if (tid == 0) cnt_s = 0;
        __syncthreads();
        unsigned int lc = 0;
        for (int i = tid; i < m; i += 256) lc += (ex[i] < mid) ? 1u : 0u;
        #pragma unroll
        for (int off = 32; off; off >>= 1) lc += __shfl_down(lc, off);
        if ((tid & 63) == 0) atomicAdd(&cnt_s, lc);
        __syncthreads();
        if (cnt_s >= (unsigned)kex) hi = mid; else lo = mid;
        __syncthreads();
    }
    const ull thr2 = lo;

    if (tid == 0) ns = 0;
    __syncthreads();
    for (int i = tid; i < m; i += 256) {
        if (ex[i] <= thr2) {
            const unsigned p = atomicAdd(&ns, 1u);
            if (p < (unsigned)KNN) sel[p] = ex[i];
        }
    }
    __syncthreads();

    if (tid == 0) {
        for (int a = 1; a < kex; a++) {
            const ull xk = sel[a];
            int b = a - 1;
            while (b >= 0 && sel[b] > xk) { sel[b + 1] = sel[b]; b--; }
            sel[b + 1] = xk;
        }
    }
    __syncthreads();
    if (tid < kex) vv[tid] = values[(unsigned)(sel[tid] & 0xFFFFFFFFull)];
    __syncthreads();

    if (tid == 0) {
        const float d0 = fmaxf(__uint_as_float((unsigned)(sel[0] >> 32)), 0.f);
        float res;
        if (d0 == 0.f) {
            res = vv[0];
        } else {
            float S = 0.f;
            for (int i = 0; i < kex; i++) {
                const float di = fmaxf(__uint_as_float((unsigned)(sel[i] >> 32)), 0.f);
                S += 1.f / (di + DELTA);
            }
            float o = 0.f;
            for (int i = 0; i < kex; i++) {
                const float di = fmaxf(__uint_as_float((unsigned)(sel[i] >> 32)), 0.f);
                const float w = 1.f / (di + DELTA);
                o += (w / S) * vv[i];
            }
            res = o;
        }
        out[q] = res;
    }
}

// ================================================================ launcher
extern "C" void kernel_launch(void* const* d_in, const int* in_sizes, int n_in,
                              void* d_out, int out_size, void* d_ws, size_t ws_size,
                              hipStream_t stream) {
    const float* qry    = (const float*)d_in[0];   // [1024,128]
    const float* keys   = (const float*)d_in[1];   // [200000,128]
    const float* values = (const float*)d_in[2];   // [200000,1]
    float* out = (float*)d_out;
    char* ws = (char*)d_ws;

    const size_t KF_OFF   = 0;
    const size_t QF_OFF   = KF_OFF  + (size_t)NKP * DIM * 2;    // 51,216,384
    const size_t KSQ_OFF  = QF_OFF  + (size_t)N_Q * DIM * 2;    // +262,144
    const size_t QSQ_OFF  = KSQ_OFF + (size_t)NKP * 4;          // +800,256
    const size_t TAU_OFF  = QSQ_OFF + 4096;
    const size_t SC_OFF   = TAU_OFF + 4096;
    const size_t OVFC_OFF = SC_OFF  + (size_t)SAMPLES * DIM * 4; // +1 MB
    const size_t OVF_OFF  = OVFC_OFF + 4096;
    const size_t CNT2_OFF = OVF_OFF + (size_t)OVFCAP * 8;        // +512 KB
    const size_t CAND2_OFF= CNT2_OFF + (size_t)NSTRIP * N_Q * 4; // +256 KB
    // cand2: 64 * 1024 * 64 * 8 = 33.5 MB ; total ~87 MB

    ushort* Kf  = (ushort*)(ws + KF_OFF);
    ushort* Qf  = (ushort*)(ws + QF_OFF);
    float*  ksq = (float*)(ws + KSQ_OFF);
    float*  qsq = (float*)(ws + QSQ_OFF);
    float*  tau = (float*)(ws + TAU_OFF);
    float*  Sc  = (float*)(ws + SC_OFF);
    unsigned int* ovf_cnt = (unsigned int*)(ws + OVFC_OFF);
    uint2*  ovf  = (uint2*)(ws + OVF_OFF);
    unsigned int* cnt2 = (unsigned int*)(ws + CNT2_OFF);
    uint2*  cand2 = (uint2*)(ws + CAND2_OFF);

    const int PREP_BLOCKS = (int)((NKP / 16 + N_Q / 16 + 3) / 4);   // 3142

    hipLaunchKernelGGL(gather_kernel, dim3(128), dim3(256), 0, stream, keys, Sc, ovf_cnt);
    hipLaunchKernelGGL(tau_kernel, dim3(N_Q / 4), dim3(256), 0, stream, qry, Sc, tau, SAMPLE_RANK);
    hipLaunchKernelGGL(prep_kernel, dim3(PREP_BLOCKS), dim3(256), 0, stream,
                       qry, keys, Kf, Qf, ksq, qsq);
    hipLaunchKernelGGL(mfma_filter_kernel, dim3(8 * NSTRIP), dim3(256), 0, stream,
                       Qf, Kf, ksq, qsq, tau, cand2, cnt2, ovf, ovf_cnt);
    hipLaunchKernelGGL(select_exact_kernel, dim3(N_Q), dim3(256), 0, stream,
                       cand2, cnt2, ovf, ovf_cnt, keys, qry, ksq, qsq, values, out);
}

// Round 6
// 379.312 us; speedup vs baseline: 1.6134x; 1.1310x over previous
//
#include <hip/hip_runtime.h>
#include <stdint.h>

#define N_KEYS 200000
#define N_Q    1024
#define DIM    128
#define KNN    50
#define DELTA  1e-3f

#define NKP     200064                 // 1563 * 128 padded keys
#define KTILES2 1563
#define NSTRIP  64
#define STRIP_L 24                     // 1563 = 27*25 + 37*24
#define STRIP_R 27
#define SAMPLES        2048
#define SAMPLE_STRIDE  97
#define SAMPLE_RANK    8
#define CAP2    3072
#define SEG     64                     // per (strip,query) candidate slots
#define OVFCAP  65536
#define BANDW   0.125f                 // sure/band split half-width (>= 2*e_fp16)
#define TSLACK  0.25f                  // tau filter slack for fp16 approx error

typedef __attribute__((ext_vector_type(8))) _Float16 f16x8;
typedef __attribute__((ext_vector_type(4))) float f32x4;
typedef unsigned long long ull;

#define GLD16(gsrc, ldst) __builtin_amdgcn_global_load_lds( \
    (const __attribute__((address_space(1))) unsigned int*)(gsrc), \
    (__attribute__((address_space(3))) unsigned int*)(ldst), 16, 0, 0)

// ================================================================ prep: fp32 -> f16 fragment-tiled + row sq-sums
__global__ void prep_kernel(const float* __restrict__ qry, const float* __restrict__ keys,
                            ushort* __restrict__ Kf, ushort* __restrict__ Qf,
                            float* __restrict__ ksq, float* __restrict__ qsq) {
    const int wave = threadIdx.x >> 6, lane = threadIdx.x & 63;
    const long NKG = NKP / 16;              // 12504
    const long NQG = N_Q / 16;              // 64
    const long grp = (long)blockIdx.x * 4 + wave;
    if (grp >= NKG + NQG) return;
    const bool isq = (grp >= NKG);
    const long lgrp = isq ? (grp - NKG) : grp;
    const long row = lgrp * 16 + (lane & 15);
    const int  hi  = lane >> 4;
    const bool valid = isq || (row < N_KEYS);
    const float* src = isq ? (qry + row * DIM) : (keys + (valid ? row * DIM : 0));

    float ss = 0.f;
    uint4 hv[4];
    #pragma unroll
    for (int s = 0; s < 4; ++s) {
        float4 a, b;
        if (valid) {
            const float4* p = (const float4*)(src + s * 32 + hi * 8);
            a = p[0]; b = p[1];
        } else {
            a = make_float4(0.f, 0.f, 0.f, 0.f); b = a;
        }
        ss = fmaf(a.x, a.x, ss); ss = fmaf(a.y, a.y, ss);
        ss = fmaf(a.z, a.z, ss); ss = fmaf(a.w, a.w, ss);
        ss = fmaf(b.x, b.x, ss); ss = fmaf(b.y, b.y, ss);
        ss = fmaf(b.z, b.z, ss); ss = fmaf(b.w, b.w, ss);
        const float v[8] = {a.x, a.y, a.z, a.w, b.x, b.y, b.z, b.w};
        unsigned h[8];
        #pragma unroll
        for (int j = 0; j < 8; ++j) {
            _Float16 t = (_Float16)v[j];
            h[j] = (unsigned)__builtin_bit_cast(unsigned short, t);
        }
        hv[s].x = h[0] | (h[1] << 16); hv[s].y = h[2] | (h[3] << 16);
        hv[s].z = h[4] | (h[5] << 16); hv[s].w = h[6] | (h[7] << 16);
    }
    ss += __shfl_xor(ss, 16);
    ss += __shfl_xor(ss, 32);

    ushort* dst = isq ? Qf : Kf;
    #pragma unroll
    for (int s = 0; s < 4; ++s)
        *(uint4*)(dst + (size_t)(lgrp * 4 + s) * 512 + lane * 8) = hv[s];

    if (lane < 16) {
        if (isq) qsq[row] = ss;
        else if (row < NKP) ksq[row] = valid ? ss : 3.0e38f;
    }
}

// ================================================================ gather sampled rows -> compact buffer (+ ovf_cnt init)
__global__ void gather_kernel(const float* __restrict__ keys, float* __restrict__ Sc,
                              unsigned int* __restrict__ ovf_cnt) {
    if (blockIdx.x == 0 && threadIdx.x == 0) *ovf_cnt = 0u;
    int f = blockIdx.x * 512 + threadIdx.x;
    #pragma unroll
    for (int p = 0; p < 2; ++p, f += 256) {
        const int row = f >> 5, c4 = f & 31;
        ((float4*)Sc)[f] = ((const float4*)(keys + (size_t)row * SAMPLE_STRIDE * DIM))[c4];
    }
}

// ================================================================ per-query sampled threshold, 4 queries/block
__global__ void tau_kernel(const float* __restrict__ qry, const float* __restrict__ Sc,
                           float* __restrict__ tau0, int rank) {
    __shared__ float Qs[4][DIM];
    __shared__ float Ds[4][SAMPLES];
    const int q0 = blockIdx.x * 4, tid = threadIdx.x;
    if (tid < 128) ((float4*)&Qs[0][0])[tid] = ((const float4*)(qry + (size_t)q0 * DIM))[tid];
    __syncthreads();

    const int sub = tid & 15, grp = tid >> 4;
    for (int s = grp; s < SAMPLES; s += 16) {
        const float4* kr = (const float4*)(Sc + (size_t)s * DIM);
        const float4 a = kr[sub * 2], b = kr[sub * 2 + 1];
        #pragma unroll
        for (int qi = 0; qi < 4; ++qi) {
            const float4 qa = ((float4*)&Qs[qi][0])[sub * 2];
            const float4 qb = ((float4*)&Qs[qi][0])[sub * 2 + 1];
            float t, acc;
            t = qa.x - a.x; acc = t * t;
            t = qa.y - a.y; acc = fmaf(t, t, acc);
            t = qa.z - a.z; acc = fmaf(t, t, acc);
            t = qa.w - a.w; acc = fmaf(t, t, acc);
            t = qb.x - b.x; acc = fmaf(t, t, acc);
            t = qb.y - b.y; acc = fmaf(t, t, acc);
            t = qb.z - b.z; acc = fmaf(t, t, acc);
            t = qb.w - b.w; acc = fmaf(t, t, acc);
            #pragma unroll
            for (int m = 1; m < 16; m <<= 1) acc += __shfl_xor(acc, m);
            if (sub == 0) Ds[qi][s] = acc;
        }
    }
    __syncthreads();

    const int wave = tid >> 6, lane = tid & 63;
    const float* D = Ds[wave];
    unsigned int v = 0;
    for (int bit = 30; bit >= 0; bit--) {
        const unsigned int tbits = v | (1u << bit);
        const float tf = __uint_as_float(tbits);
        unsigned int lc = 0;
        for (int i = lane; i < SAMPLES; i += 64) lc += (D[i] < tf) ? 1u : 0u;
        #pragma unroll
        for (int m = 1; m < 64; m <<= 1) lc += __shfl_xor(lc, m);
        if (lc < (unsigned)rank) v = tbits;
    }
    if (lane == 0) tau0[q0 + wave] = __uint_as_float(v);
}

// ================================================================ f16 MFMA distance GEMM + filter
__global__ __launch_bounds__(256, 2)
void mfma_filter_kernel(const ushort* __restrict__ Qf, const ushort* __restrict__ Kf,
                        const float* __restrict__ ksq_g, const float* __restrict__ qsq_g,
                        const float* __restrict__ tau_g,
                        uint2* __restrict__ cand2, unsigned int* __restrict__ cnt2,
                        uint2* __restrict__ ovf, unsigned int* __restrict__ ovf_cnt) {
    __shared__ ushort Blds[2][16384];     // 2 x 32 KB K-tile double buffer
    __shared__ unsigned int lcnt[128];    // per-query local segment counts

    const int wg = blockIdx.x;
    const int qt = wg >> 6;
    const int strip = wg & 63;            // strip-sharing blocks: wg%8 == strip%8 -> same XCD
    int t0, len;
    if (strip < STRIP_R) { t0 = strip * (STRIP_L + 1); len = STRIP_L + 1; }
    else { t0 = STRIP_R * (STRIP_L + 1) + (strip - STRIP_R) * STRIP_L; len = STRIP_L; }

    const int qbase = qt * 128;
    const int tid = threadIdx.x, lane = tid & 63, wave = tid >> 6;
    const int wr = wave >> 1, wc = wave & 1;
    const int col = lane & 15, rowb = (lane >> 4) * 4;

    // Q fragments -> registers
    f16x8 af[4][4];
    {
        const ushort* qsrc = Qf + (size_t)qt * 16384 + lane * 8;
        #pragma unroll
        for (int i = 0; i < 4; ++i)
            #pragma unroll
            for (int s = 0; s < 4; ++s)
                af[i][s] = *(const f16x8*)(qsrc + ((wr * 4 + i) * 4 + s) * 512);
    }
    float thr_r[4][4], qsq_r[4][4];
    #pragma unroll
    for (int i = 0; i < 4; ++i)
        #pragma unroll
        for (int r = 0; r < 4; ++r) {
            const int qg = qbase + wr * 64 + i * 16 + rowb + r;
            const float qs = qsq_g[qg];
            qsq_r[i][r] = qs;
            thr_r[i][r] = tau_g[qg] + TSLACK - qs;
        }

    if (tid < 128) lcnt[tid] = 0u;
    {   // prologue stage -> buf 0
        const ushort* src = Kf + (size_t)t0 * 16384 + lane * 8;
        #pragma unroll
        for (int c = 0; c < 8; ++c)
            GLD16(src + (wave * 8 + c) * 512, &Blds[0][(wave * 8 + c) * 512]);
    }
    __syncthreads();

    for (int t = 0; t < len; ++t) {
        const int kt = t0 + t;
        const int cur = t & 1;

        float ksq4[4];
        #pragma unroll
        for (int j = 0; j < 4; ++j)
            ksq4[j] = ksq_g[kt * 128 + wc * 64 + j * 16 + col];

        if (t + 1 < len) {
            const ushort* src = Kf + (size_t)(kt + 1) * 16384 + lane * 8;
            #pragma unroll
            for (int c = 0; c < 8; ++c)
                GLD16(src + (wave * 8 + c) * 512, &Blds[cur ^ 1][(wave * 8 + c) * 512]);
        }

        f32x4 acc[4][4];
        #pragma unroll
        for (int i = 0; i < 4; ++i)
            #pragma unroll
            for (int j = 0; j < 4; ++j) acc[i][j] = (f32x4){0.f, 0.f, 0.f, 0.f};

        #pragma unroll
        for (int s = 0; s < 4; ++s) {
            f16x8 bfr[4];
            #pragma unroll
            for (int j = 0; j < 4; ++j)
                bfr[j] = *(const f16x8*)&Blds[cur][((wc * 4 + j) * 4 + s) * 512 + lane * 8];
            #pragma unroll
            for (int i = 0; i < 4; ++i)
                #pragma unroll
                for (int j = 0; j < 4; ++j)
                    acc[i][j] = __builtin_amdgcn_mfma_f32_16x16x32_f16(af[i][s], bfr[j], acc[i][j], 0, 0, 0);
        }

        // epilogue: LDS-slot append + fire-and-forget store (no global atomics)
        #pragma unroll
        for (int i = 0; i < 4; ++i) {
            #pragma unroll
            for (int j = 0; j < 4; ++j) {
                #pragma unroll
                for (int r = 0; r < 4; ++r) {
                    const float mm = fmaf(-2.f, acc[i][j][r], ksq4[j]);
                    if (mm < thr_r[i][r]) {
                        const int ql = wr * 64 + i * 16 + rowb + r;
                        const unsigned kg = (unsigned)(kt * 128 + wc * 64 + j * 16 + col);
                        const float dist = qsq_r[i][r] + mm;
                        const unsigned slot = atomicAdd(&lcnt[ql], 1u);
                        if (slot < (unsigned)SEG) {
                            cand2[((size_t)strip * N_Q + qbase + ql) * SEG + slot] =
                                make_uint2(__float_as_uint(dist), kg);
                        } else {
                            const unsigned op = atomicAdd(ovf_cnt, 1u);
                            if (op < (unsigned)OVFCAP)
                                ovf[op] = make_uint2(__float_as_uint(dist),
                                                     ((unsigned)(qbase + ql) << 18) | kg);
                        }
                    }
                }
            }
        }
        __syncthreads();
    }

    if (tid < 128) {
        const unsigned c = lcnt[tid];
        cnt2[(size_t)strip * N_Q + qbase + tid] = (c > (unsigned)SEG) ? (unsigned)SEG : c;
    }
}

// ================================================================ select v3: radix a50 -> band-only exact recompute -> IDW
__global__ __launch_bounds__(256)
void select_kernel(const uint2* __restrict__ cand2, const unsigned int* __restrict__ cnt2,
                   const uint2* __restrict__ ovf, const unsigned int* __restrict__ ovf_cnt,
                   const float* __restrict__ keys, const float* __restrict__ qry,
                   const float* __restrict__ ksq_g, const float* __restrict__ qsq_g,
                   const float* __restrict__ values, float* __restrict__ out) {
    __shared__ float Qs[DIM];
    __shared__ unsigned dbits[CAP2];
    __shared__ unsigned didx[CAP2];
    __shared__ unsigned offs[NSTRIP + 1];
    __shared__ unsigned band_idx[128];
    __shared__ ull bandkey[128];
    __shared__ ull sel[64];
    __shared__ float vv[64];
    __shared__ unsigned int ns_sure, nb, ns_extra, a50_s;
    const int q = blockIdx.x, tid = threadIdx.x;

    if (tid < 32) ((float4*)Qs)[tid] = ((const float4*)(qry + (size_t)q * DIM))[tid];
    if (tid == 0) { ns_sure = 0; nb = 0; ns_extra = 0; }

    // segment prefix-scan (wave 0)
    if (tid < NSTRIP) {
        unsigned sc = cnt2[(size_t)tid * N_Q + q];
        #pragma unroll
        for (int d = 1; d < NSTRIP; d <<= 1) {
            unsigned n = __shfl_up(sc, d);
            if (tid >= d) sc += n;
        }
        offs[tid + 1] = sc;
        if (tid == 0) offs[0] = 0;
    }
    __syncthreads();

    // copy segments: 4 threads per strip
    {
        const int s = tid >> 2, sub = tid & 3;
        const unsigned o = offs[s], n = offs[s + 1] - o;
        const uint2* seg = cand2 + ((size_t)s * N_Q + q) * SEG;
        for (unsigned i = sub; i < n; i += 4) {
            const unsigned dsti = o + i;
            if (dsti < (unsigned)CAP2) {
                const uint2 e = seg[i];
                dbits[dsti] = e.x; didx[dsti] = e.y;
            }
        }
    }
    // rare overflow entries
    {
        const unsigned no = min(*ovf_cnt, (unsigned)OVFCAP);
        for (unsigned i = tid; i < no; i += 256) {
            const uint2 e = ovf[i];
            if ((e.y >> 18) == (unsigned)q) {
                const unsigned p = atomicAdd(&ns_extra, 1u);
                const unsigned dsti = offs[NSTRIP] + p;
                if (dsti < (unsigned)CAP2) { dbits[dsti] = e.x; didx[dsti] = e.y & 0x3FFFFu; }
            }
        }
    }
    __syncthreads();
    const int c = min((int)(offs[NSTRIP] + ns_extra), CAP2);
    const int ksel = min(KNN, c);
    if (ksel == 0) { if (tid == 0) out[q] = 0.f; return; }

    // ---- radix select a50 = ksel-th smallest approx dist (wave-redundant, barrier-free)
    const int lane = tid & 63;
    {
        unsigned v = 0;
        for (int bit = 30; bit >= 0; bit--) {
            const unsigned tb = v | (1u << bit);
            unsigned lc = 0;
            for (int i = lane; i < c; i += 64) lc += (dbits[i] < tb) ? 1u : 0u;
            #pragma unroll
            for (int m = 1; m < 64; m <<= 1) lc += __shfl_xor(lc, m);
            if (lc < (unsigned)ksel) v = tb;
        }
        if (tid == 0) a50_s = v;
    }
    __syncthreads();
    const float a50 = __uint_as_float(a50_s);
    const float lo_cut = a50 - BANDW, hi_cut = a50 + BANDW;

    // ---- classify: sure (approx) / band (needs exact)
    for (int i = tid; i < c; i += 256) {
        const float A = __uint_as_float(dbits[i]);
        if (A < lo_cut) {
            const unsigned p = atomicAdd(&ns_sure, 1u);
            if (p < 64u) sel[p] = ((ull)dbits[i] << 32) | didx[i];
        } else if (A <= hi_cut) {
            const unsigned p = atomicAdd(&nb, 1u);
            if (p < 128u) band_idx[p] = didx[i];
        }
    }
    __syncthreads();
    const int nsure = min((int)ns_sure, 64);
    const int nband = min((int)nb, 128);
    const int need = min(ksel - nsure, nband);

    // ---- exact fp32 recompute for band (4 threads / element)
    const float qsq = qsq_g[q];
    for (int base = 0; base < nband; base += 64) {
        const int j = base + (tid >> 2);
        if (j < nband) {
            const int part = tid & 3;
            const int kidx = (int)band_idx[j];
            const float* kr = keys + (size_t)kidx * DIM + part * 32;
            const float* qp = Qs + part * 32;
            float acc = 0.f;
            #pragma unroll
            for (int d4 = 0; d4 < 8; ++d4) {
                const float4 kv = ((const float4*)kr)[d4];
                const float4 qv = ((const float4*)qp)[d4];
                acc = fmaf(qv.x, kv.x, acc); acc = fmaf(qv.y, kv.y, acc);
                acc = fmaf(qv.z, kv.z, acc); acc = fmaf(qv.w, kv.w, acc);
            }
            acc += __shfl_xor(acc, 1);
            acc += __shfl_xor(acc, 2);
            if (part == 0) {
                const float mm = fmaf(-2.f, acc, ksq_g[kidx]);
                const float dist = qsq + mm;
                bandkey[j] = ((ull)__float_as_uint(dist) << 32) | (unsigned)kidx;
            }
        }
    }
    __syncthreads();

    // ---- rank-place best `need` band elements (deterministic slots)
    if (tid < nband) {
        const ull mykey = bandkey[tid];
        int rank = 0;
        for (int i = 0; i < nband; ++i) rank += (bandkey[i] < mykey) ? 1 : 0;
        if (rank < need) sel[nsure + rank] = mykey;
    }
    __syncthreads();
    const int nfinal = nsure + max(need, 0);

    if (tid == 0) {  // deterministic order: insertion sort ascending (dist, idx)
        for (int a = 1; a < nfinal; a++) {
            const ull xk = sel[a];
            int b = a - 1;
            while (b >= 0 && sel[b] > xk) { sel[b + 1] = sel[b]; b--; }
            sel[b + 1] = xk;
        }
    }
    __syncthreads();
    if (tid < nfinal) vv[tid] = values[(unsigned)(sel[tid] & 0xFFFFFFFFull)];
    __syncthreads();

    if (tid == 0) {
        const float d0 = fmaxf(__uint_as_float((unsigned)(sel[0] >> 32)), 0.f);
        float res;
        if (d0 == 0.f) {
            res = vv[0];
        } else {
            float S = 0.f;
            for (int i = 0; i < nfinal; i++) {
                const float di = fmaxf(__uint_as_float((unsigned)(sel[i] >> 32)), 0.f);
                S += 1.f / (di + DELTA);
            }
            float o = 0.f;
            for (int i = 0; i < nfinal; i++) {
                const float di = fmaxf(__uint_as_float((unsigned)(sel[i] >> 32)), 0.f);
                const float w = 1.f / (di + DELTA);
                o += (w / S) * vv[i];
            }
            res = o;
        }
        out[q] = res;
    }
}

// ================================================================ launcher
extern "C" void kernel_launch(void* const* d_in, const int* in_sizes, int n_in,
                              void* d_out, int out_size, void* d_ws, size_t ws_size,
                              hipStream_t stream) {
    const float* qry    = (const float*)d_in[0];   // [1024,128]
    const float* keys   = (const float*)d_in[1];   // [200000,128]
    const float* values = (const float*)d_in[2];   // [200000,1]
    float* out = (float*)d_out;
    char* ws = (char*)d_ws;

    const size_t KF_OFF   = 0;
    const size_t QF_OFF   = KF_OFF  + (size_t)NKP * DIM * 2;    // 51,216,384
    const size_t KSQ_OFF  = QF_OFF  + (size_t)N_Q * DIM * 2;    // +262,144
    const size_t QSQ_OFF  = KSQ_OFF + (size_t)NKP * 4;          // +800,256
    const size_t TAU_OFF  = QSQ_OFF + 4096;
    const size_t SC_OFF   = TAU_OFF + 4096;
    const size_t OVFC_OFF = SC_OFF  + (size_t)SAMPLES * DIM * 4; // +1 MB
    const size_t OVF_OFF  = OVFC_OFF + 4096;
    const size_t CNT2_OFF = OVF_OFF + (size_t)OVFCAP * 8;        // +512 KB
    const size_t CAND2_OFF= CNT2_OFF + (size_t)NSTRIP * N_Q * 4; // +256 KB
    // cand2: 64 * 1024 * 64 * 8 = 33.5 MB ; total ~87 MB

    ushort* Kf  = (ushort*)(ws + KF_OFF);
    ushort* Qf  = (ushort*)(ws + QF_OFF);
    float*  ksq = (float*)(ws + KSQ_OFF);
    float*  qsq = (float*)(ws + QSQ_OFF);
    float*  tau = (float*)(ws + TAU_OFF);
    float*  Sc  = (float*)(ws + SC_OFF);
    unsigned int* ovf_cnt = (unsigned int*)(ws + OVFC_OFF);
    uint2*  ovf  = (uint2*)(ws + OVF_OFF);
    unsigned int* cnt2 = (unsigned int*)(ws + CNT2_OFF);
    uint2*  cand2 = (uint2*)(ws + CAND2_OFF);

    const int PREP_BLOCKS = (int)((NKP / 16 + N_Q / 16 + 3) / 4);   // 3142

    hipLaunchKernelGGL(gather_kernel, dim3(128), dim3(256), 0, stream, keys, Sc, ovf_cnt);
    hipLaunchKernelGGL(tau_kernel, dim3(N_Q / 4), dim3(256), 0, stream, qry, Sc, tau, SAMPLE_RANK);
    hipLaunchKernelGGL(prep_kernel, dim3(PREP_BLOCKS), dim3(256), 0, stream,
                       qry, keys, Kf, Qf, ksq, qsq);
    hipLaunchKernelGGL(mfma_filter_kernel, dim3(8 * NSTRIP), dim3(256), 0, stream,
                       Qf, Kf, ksq, qsq, tau, cand2, cnt2, ovf, ovf_cnt);
    hipLaunchKernelGGL(select_kernel, dim3(N_Q), dim3(256), 0, stream,
                       cand2, cnt2, ovf, ovf_cnt, keys, qry, ksq, qsq, values, out);
}

// Round 7
// 254.325 us; speedup vs baseline: 2.4063x; 1.4914x over previous
//
#include <hip/hip_runtime.h>
#include <stdint.h>

#define N_KEYS 200000
#define N_Q    1024
#define DIM    128
#define KNN    50
#define DELTA  1e-3f

#define NKP     200064                 // 1563 * 128 padded keys
#define KTILES2 1563
#define NSTRIP  64
#define STRIP_L 24                     // 1563 = 27*25 + 37*24
#define STRIP_R 27
#define SAMPLES 2048
#define NSTILE  16                     // 16 sample tiles x 128 keys
#define STILE_STRIDE 97                // tile idx = s*97 (max 1455 < 1563, keys < 186368)
#define SAMPLE_RANK 8
#define CAP2    3072
#define SEG     64                     // per (strip,query) candidate slots
#define OVFCAP  65536
#define BANDW   0.125f                 // sure/band split half-width (>= 2*e_fp16)
#define TSLACK  0.25f                  // tau filter slack for fp16 approx error

typedef __attribute__((ext_vector_type(8))) _Float16 f16x8;
typedef __attribute__((ext_vector_type(4))) float f32x4;
typedef unsigned long long ull;

#define GLD16(gsrc, ldst) __builtin_amdgcn_global_load_lds( \
    (const __attribute__((address_space(1))) unsigned int*)(gsrc), \
    (__attribute__((address_space(3))) unsigned int*)(ldst), 16, 0, 0)

// ================================================================ prep: fp32 -> f16 fragment-tiled + row sq-sums
__global__ void prep_kernel(const float* __restrict__ qry, const float* __restrict__ keys,
                            ushort* __restrict__ Kf, ushort* __restrict__ Qf,
                            float* __restrict__ ksq, float* __restrict__ qsq,
                            unsigned int* __restrict__ ovf_cnt) {
    if (blockIdx.x == 0 && threadIdx.x == 0) *ovf_cnt = 0u;
    const int wave = threadIdx.x >> 6, lane = threadIdx.x & 63;
    const long NKG = NKP / 16;              // 12504
    const long NQG = N_Q / 16;              // 64
    const long grp = (long)blockIdx.x * 4 + wave;
    if (grp >= NKG + NQG) return;
    const bool isq = (grp >= NKG);
    const long lgrp = isq ? (grp - NKG) : grp;
    const long row = lgrp * 16 + (lane & 15);
    const int  hi  = lane >> 4;
    const bool valid = isq || (row < N_KEYS);
    const float* src = isq ? (qry + row * DIM) : (keys + (valid ? row * DIM : 0));

    float ss = 0.f;
    uint4 hv[4];
    #pragma unroll
    for (int s = 0; s < 4; ++s) {
        float4 a, b;
        if (valid) {
            const float4* p = (const float4*)(src + s * 32 + hi * 8);
            a = p[0]; b = p[1];
        } else {
            a = make_float4(0.f, 0.f, 0.f, 0.f); b = a;
        }
        ss = fmaf(a.x, a.x, ss); ss = fmaf(a.y, a.y, ss);
        ss = fmaf(a.z, a.z, ss); ss = fmaf(a.w, a.w, ss);
        ss = fmaf(b.x, b.x, ss); ss = fmaf(b.y, b.y, ss);
        ss = fmaf(b.z, b.z, ss); ss = fmaf(b.w, b.w, ss);
        const float v[8] = {a.x, a.y, a.z, a.w, b.x, b.y, b.z, b.w};
        unsigned h[8];
        #pragma unroll
        for (int j = 0; j < 8; ++j) {
            _Float16 t = (_Float16)v[j];
            h[j] = (unsigned)__builtin_bit_cast(unsigned short, t);
        }
        hv[s].x = h[0] | (h[1] << 16); hv[s].y = h[2] | (h[3] << 16);
        hv[s].z = h[4] | (h[5] << 16); hv[s].w = h[6] | (h[7] << 16);
    }
    ss += __shfl_xor(ss, 16);
    ss += __shfl_xor(ss, 32);

    ushort* dst = isq ? Qf : Kf;
    #pragma unroll
    for (int s = 0; s < 4; ++s)
        *(uint4*)(dst + (size_t)(lgrp * 4 + s) * 512 + lane * 8) = hv[s];

    if (lane < 16) {
        if (isq) qsq[row] = ss;
        else if (row < NKP) ksq[row] = valid ? ss : 3.0e38f;
    }
}

// ================================================================ tau phase A: MFMA approx distances for 16 sampled tiles
__global__ __launch_bounds__(256)
void tau_dist_kernel(const ushort* __restrict__ Qf, const ushort* __restrict__ Kf,
                     const float* __restrict__ ksq_g, const float* __restrict__ qsq_g,
                     float* __restrict__ Ds) {
    __shared__ ushort Blds[16384];
    const int qt = blockIdx.x >> 4;
    const int st = blockIdx.x & 15;
    const int ktile = st * STILE_STRIDE;
    const int qbase = qt * 128, kbase = ktile * 128;
    const int tid = threadIdx.x, lane = tid & 63, wave = tid >> 6;
    const int wr = wave >> 1, wc = wave & 1;
    const int col = lane & 15, rowb = (lane >> 4) * 4;

    {
        const ushort* src = Kf + (size_t)ktile * 16384 + lane * 8;
        #pragma unroll
        for (int c = 0; c < 8; ++c)
            GLD16(src + (wave * 8 + c) * 512, &Blds[(wave * 8 + c) * 512]);
    }
    f16x8 af[4][4];
    {
        const ushort* qsrc = Qf + (size_t)qt * 16384 + lane * 8;
        #pragma unroll
        for (int i = 0; i < 4; ++i)
            #pragma unroll
            for (int s = 0; s < 4; ++s)
                af[i][s] = *(const f16x8*)(qsrc + ((wr * 4 + i) * 4 + s) * 512);
    }
    float qsq_r[4][4];
    #pragma unroll
    for (int i = 0; i < 4; ++i)
        #pragma unroll
        for (int r = 0; r < 4; ++r)
            qsq_r[i][r] = qsq_g[qbase + wr * 64 + i * 16 + rowb + r];
    float ksq4[4];
    #pragma unroll
    for (int j = 0; j < 4; ++j)
        ksq4[j] = ksq_g[kbase + wc * 64 + j * 16 + col];
    __syncthreads();

    f32x4 acc[4][4];
    #pragma unroll
    for (int i = 0; i < 4; ++i)
        #pragma unroll
        for (int j = 0; j < 4; ++j) acc[i][j] = (f32x4){0.f, 0.f, 0.f, 0.f};
    #pragma unroll
    for (int s = 0; s < 4; ++s) {
        f16x8 bfr[4];
        #pragma unroll
        for (int j = 0; j < 4; ++j)
            bfr[j] = *(const f16x8*)&Blds[((wc * 4 + j) * 4 + s) * 512 + lane * 8];
        #pragma unroll
        for (int i = 0; i < 4; ++i)
            #pragma unroll
            for (int j = 0; j < 4; ++j)
                acc[i][j] = __builtin_amdgcn_mfma_f32_16x16x32_f16(af[i][s], bfr[j], acc[i][j], 0, 0, 0);
    }

    #pragma unroll
    for (int i = 0; i < 4; ++i) {
        #pragma unroll
        for (int j = 0; j < 4; ++j) {
            #pragma unroll
            for (int r = 0; r < 4; ++r) {
                const int ql = wr * 64 + i * 16 + rowb + r;
                const int kl = wc * 64 + j * 16 + col;
                const float dist = qsq_r[i][r] + fmaf(-2.f, acc[i][j][r], ksq4[j]);
                Ds[(size_t)(qbase + ql) * SAMPLES + st * 128 + kl] = dist;
            }
        }
    }
}

// ================================================================ tau phase B: per-query rank-8 radix select (4 q/block)
__global__ __launch_bounds__(256)
void tau_select_kernel(const float* __restrict__ Ds, float* __restrict__ tau0, int rank) {
    __shared__ float D[4][SAMPLES];     // 32 KB
    const int q0 = blockIdx.x * 4, tid = threadIdx.x;
    {
        const float4* srcv = (const float4*)(Ds + (size_t)q0 * SAMPLES);
        float4* dstv = (float4*)&D[0][0];
        for (int i = tid; i < SAMPLES; i += 256) dstv[i] = srcv[i];
    }
    __syncthreads();

    const int wave = tid >> 6, lane = tid & 63;
    const float* Dq = D[wave];
    unsigned int v = 0;
    for (int bit = 30; bit >= 0; bit--) {
        const unsigned int tbits = v | (1u << bit);
        const float tf = __uint_as_float(tbits);
        unsigned int lc = 0;
        for (int i = lane; i < SAMPLES; i += 64) lc += (Dq[i] < tf) ? 1u : 0u;
        #pragma unroll
        for (int m = 1; m < 64; m <<= 1) lc += __shfl_xor(lc, m);
        if (lc < (unsigned)rank) v = tbits;
    }
    if (lane == 0) tau0[q0 + wave] = __uint_as_float(v);
}

// ================================================================ f16 MFMA distance GEMM + filter
__global__ __launch_bounds__(256, 2)
void mfma_filter_kernel(const ushort* __restrict__ Qf, const ushort* __restrict__ Kf,
                        const float* __restrict__ ksq_g, const float* __restrict__ qsq_g,
                        const float* __restrict__ tau_g,
                        uint2* __restrict__ cand2, unsigned int* __restrict__ cnt2,
                        uint2* __restrict__ ovf, unsigned int* __restrict__ ovf_cnt) {
    __shared__ ushort Blds[2][16384];     // 2 x 32 KB K-tile double buffer
    __shared__ unsigned int lcnt[128];    // per-query local segment counts

    const int wg = blockIdx.x;
    const int qt = wg >> 6;
    const int strip = wg & 63;            // strip-sharing blocks: wg%8 == strip%8 -> same XCD
    int t0, len;
    if (strip < STRIP_R) { t0 = strip * (STRIP_L + 1); len = STRIP_L + 1; }
    else { t0 = STRIP_R * (STRIP_L + 1) + (strip - STRIP_R) * STRIP_L; len = STRIP_L; }

    const int qbase = qt * 128;
    const int tid = threadIdx.x, lane = tid & 63, wave = tid >> 6;
    const int wr = wave >> 1, wc = wave & 1;
    const int col = lane & 15, rowb = (lane >> 4) * 4;

    // Q fragments -> registers
    f16x8 af[4][4];
    {
        const ushort* qsrc = Qf + (size_t)qt * 16384 + lane * 8;
        #pragma unroll
        for (int i = 0; i < 4; ++i)
            #pragma unroll
            for (int s = 0; s < 4; ++s)
                af[i][s] = *(const f16x8*)(qsrc + ((wr * 4 + i) * 4 + s) * 512);
    }
    float thr_r[4][4], qsq_r[4][4];
    #pragma unroll
    for (int i = 0; i < 4; ++i)
        #pragma unroll
        for (int r = 0; r < 4; ++r) {
            const int qg = qbase + wr * 64 + i * 16 + rowb + r;
            const float qs = qsq_g[qg];
            qsq_r[i][r] = qs;
            thr_r[i][r] = tau_g[qg] + TSLACK - qs;
        }

    if (tid < 128) lcnt[tid] = 0u;
    {   // prologue stage -> buf 0
        const ushort* src = Kf + (size_t)t0 * 16384 + lane * 8;
        #pragma unroll
        for (int c = 0; c < 8; ++c)
            GLD16(src + (wave * 8 + c) * 512, &Blds[0][(wave * 8 + c) * 512]);
    }
    __syncthreads();

    for (int t = 0; t < len; ++t) {
        const int kt = t0 + t;
        const int cur = t & 1;

        float ksq4[4];
        #pragma unroll
        for (int j = 0; j < 4; ++j)
            ksq4[j] = ksq_g[kt * 128 + wc * 64 + j * 16 + col];

        if (t + 1 < len) {
            const ushort* src = Kf + (size_t)(kt + 1) * 16384 + lane * 8;
            #pragma unroll
            for (int c = 0; c < 8; ++c)
                GLD16(src + (wave * 8 + c) * 512, &Blds[cur ^ 1][(wave * 8 + c) * 512]);
        }

        f32x4 acc[4][4];
        #pragma unroll
        for (int i = 0; i < 4; ++i)
            #pragma unroll
            for (int j = 0; j < 4; ++j) acc[i][j] = (f32x4){0.f, 0.f, 0.f, 0.f};

        #pragma unroll
        for (int s = 0; s < 4; ++s) {
            f16x8 bfr[4];
            #pragma unroll
            for (int j = 0; j < 4; ++j)
                bfr[j] = *(const f16x8*)&Blds[cur][((wc * 4 + j) * 4 + s) * 512 + lane * 8];
            #pragma unroll
            for (int i = 0; i < 4; ++i)
                #pragma unroll
                for (int j = 0; j < 4; ++j)
                    acc[i][j] = __builtin_amdgcn_mfma_f32_16x16x32_f16(af[i][s], bfr[j], acc[i][j], 0, 0, 0);
        }

        // epilogue: LDS-slot append + fire-and-forget store (no global atomics)
        #pragma unroll
        for (int i = 0; i < 4; ++i) {
            #pragma unroll
            for (int j = 0; j < 4; ++j) {
                #pragma unroll
                for (int r = 0; r < 4; ++r) {
                    const float mm = fmaf(-2.f, acc[i][j][r], ksq4[j]);
                    if (mm < thr_r[i][r]) {
                        const int ql = wr * 64 + i * 16 + rowb + r;
                        const unsigned kg = (unsigned)(kt * 128 + wc * 64 + j * 16 + col);
                        const float dist = qsq_r[i][r] + mm;
                        const unsigned slot = atomicAdd(&lcnt[ql], 1u);
                        if (slot < (unsigned)SEG) {
                            cand2[((size_t)strip * N_Q + qbase + ql) * SEG + slot] =
                                make_uint2(__float_as_uint(dist), kg);
                        } else {
                            const unsigned op = atomicAdd(ovf_cnt, 1u);
                            if (op < (unsigned)OVFCAP)
                                ovf[op] = make_uint2(__float_as_uint(dist),
                                                     ((unsigned)(qbase + ql) << 18) | kg);
                        }
                    }
                }
            }
        }
        __syncthreads();
    }

    if (tid < 128) {
        const unsigned c = lcnt[tid];
        cnt2[(size_t)strip * N_Q + qbase + tid] = (c > (unsigned)SEG) ? (unsigned)SEG : c;
    }
}

// ================================================================ select: radix a50 -> band-only exact recompute -> IDW
__global__ __launch_bounds__(256)
void select_kernel(const uint2* __restrict__ cand2, const unsigned int* __restrict__ cnt2,
                   const uint2* __restrict__ ovf, const unsigned int* __restrict__ ovf_cnt,
                   const float* __restrict__ keys, const float* __restrict__ qry,
                   const float* __restrict__ ksq_g, const float* __restrict__ qsq_g,
                   const float* __restrict__ values, float* __restrict__ out) {
    __shared__ float Qs[DIM];
    __shared__ unsigned dbits[CAP2];
    __shared__ unsigned didx[CAP2];
    __shared__ unsigned offs[NSTRIP + 1];
    __shared__ unsigned band_idx[128];
    __shared__ ull bandkey[128];
    __shared__ ull sel[64];
    __shared__ float vv[64];
    __shared__ unsigned int ns_sure, nb, ns_extra, a50_s;
    const int q = blockIdx.x, tid = threadIdx.x;

    if (tid < 32) ((float4*)Qs)[tid] = ((const float4*)(qry + (size_t)q * DIM))[tid];
    if (tid == 0) { ns_sure = 0; nb = 0; ns_extra = 0; }

    // segment prefix-scan (wave 0)
    if (tid < NSTRIP) {
        unsigned sc = cnt2[(size_t)tid * N_Q + q];
        #pragma unroll
        for (int d = 1; d < NSTRIP; d <<= 1) {
            unsigned n = __shfl_up(sc, d);
            if (tid >= d) sc += n;
        }
        offs[tid + 1] = sc;
        if (tid == 0) offs[0] = 0;
    }
    __syncthreads();

    // copy segments: 4 threads per strip
    {
        const int s = tid >> 2, sub = tid & 3;
        const unsigned o = offs[s], n = offs[s + 1] - o;
        const uint2* seg = cand2 + ((size_t)s * N_Q + q) * SEG;
        for (unsigned i = sub; i < n; i += 4) {
            const unsigned dsti = o + i;
            if (dsti < (unsigned)CAP2) {
                const uint2 e = seg[i];
                dbits[dsti] = e.x; didx[dsti] = e.y;
            }
        }
    }
    // rare overflow entries
    {
        const unsigned no = min(*ovf_cnt, (unsigned)OVFCAP);
        for (unsigned i = tid; i < no; i += 256) {
            const uint2 e = ovf[i];
            if ((e.y >> 18) == (unsigned)q) {
                const unsigned p = atomicAdd(&ns_extra, 1u);
                const unsigned dsti = offs[NSTRIP] + p;
                if (dsti < (unsigned)CAP2) { dbits[dsti] = e.x; didx[dsti] = e.y & 0x3FFFFu; }
            }
        }
    }
    __syncthreads();
    const int c = min((int)(offs[NSTRIP] + ns_extra), CAP2);
    const int ksel = min(KNN, c);
    if (ksel == 0) { if (tid == 0) out[q] = 0.f; return; }

    // ---- radix select a50 = ksel-th smallest approx dist (wave-redundant, barrier-free)
    const int lane = tid & 63;
    {
        unsigned v = 0;
        for (int bit = 30; bit >= 0; bit--) {
            const unsigned tb = v | (1u << bit);
            unsigned lc = 0;
            for (int i = lane; i < c; i += 64) lc += (dbits[i] < tb) ? 1u : 0u;
            #pragma unroll
            for (int m = 1; m < 64; m <<= 1) lc += __shfl_xor(lc, m);
            if (lc < (unsigned)ksel) v = tb;
        }
        if (tid == 0) a50_s = v;
    }
    __syncthreads();
    const float a50 = __uint_as_float(a50_s);
    const float lo_cut = a50 - BANDW, hi_cut = a50 + BANDW;

    // ---- classify: sure (approx) / band (needs exact)
    for (int i = tid; i < c; i += 256) {
        const float A = __uint_as_float(dbits[i]);
        if (A < lo_cut) {
            const unsigned p = atomicAdd(&ns_sure, 1u);
            if (p < 64u) sel[p] = ((ull)dbits[i] << 32) | didx[i];
        } else if (A <= hi_cut) {
            const unsigned p = atomicAdd(&nb, 1u);
            if (p < 128u) band_idx[p] = didx[i];
        }
    }
    __syncthreads();
    const int nsure = min((int)ns_sure, 64);
    const int nband = min((int)nb, 128);
    const int need = min(ksel - nsure, nband);

    // ---- exact fp32 recompute for band (4 threads / element)
    const float qsq = qsq_g[q];
    for (int base = 0; base < nband; base += 64) {
        const int j = base + (tid >> 2);
        if (j < nband) {
            const int part = tid & 3;
            const int kidx = (int)band_idx[j];
            const float* kr = keys + (size_t)kidx * DIM + part * 32;
            const float* qp = Qs + part * 32;
            float acc = 0.f;
            #pragma unroll
            for (int d4 = 0; d4 < 8; ++d4) {
                const float4 kv = ((const float4*)kr)[d4];
                const float4 qv = ((const float4*)qp)[d4];
                acc = fmaf(qv.x, kv.x, acc); acc = fmaf(qv.y, kv.y, acc);
                acc = fmaf(qv.z, kv.z, acc); acc = fmaf(qv.w, kv.w, acc);
            }
            acc += __shfl_xor(acc, 1);
            acc += __shfl_xor(acc, 2);
            if (part == 0) {
                const float mm = fmaf(-2.f, acc, ksq_g[kidx]);
                const float dist = qsq + mm;
                bandkey[j] = ((ull)__float_as_uint(dist) << 32) | (unsigned)kidx;
            }
        }
    }
    __syncthreads();

    // ---- rank-place best `need` band elements (deterministic slots)
    if (tid < nband) {
        const ull mykey = bandkey[tid];
        int rank = 0;
        for (int i = 0; i < nband; ++i) rank += (bandkey[i] < mykey) ? 1 : 0;
        if (rank < need) sel[nsure + rank] = mykey;
    }
    __syncthreads();
    const int nfinal = nsure + max(need, 0);

    if (tid == 0) {  // deterministic order: insertion sort ascending (dist, idx)
        for (int a = 1; a < nfinal; a++) {
            const ull xk = sel[a];
            int b = a - 1;
            while (b >= 0 && sel[b] > xk) { sel[b + 1] = sel[b]; b--; }
            sel[b + 1] = xk;
        }
    }
    __syncthreads();
    if (tid < nfinal) vv[tid] = values[(unsigned)(sel[tid] & 0xFFFFFFFFull)];
    __syncthreads();

    if (tid == 0) {
        const float d0 = fmaxf(__uint_as_float((unsigned)(sel[0] >> 32)), 0.f);
        float res;
        if (d0 == 0.f) {
            res = vv[0];
        } else {
            float S = 0.f;
            for (int i = 0; i < nfinal; i++) {
                const float di = fmaxf(__uint_as_float((unsigned)(sel[i] >> 32)), 0.f);
                S += 1.f / (di + DELTA);
            }
            float o = 0.f;
            for (int i = 0; i < nfinal; i++) {
                const float di = fmaxf(__uint_as_float((unsigned)(sel[i] >> 32)), 0.f);
                const float w = 1.f / (di + DELTA);
                o += (w / S) * vv[i];
            }
            res = o;
        }
        out[q] = res;
    }
}

// ================================================================ launcher
extern "C" void kernel_launch(void* const* d_in, const int* in_sizes, int n_in,
                              void* d_out, int out_size, void* d_ws, size_t ws_size,
                              hipStream_t stream) {
    const float* qry    = (const float*)d_in[0];   // [1024,128]
    const float* keys   = (const float*)d_in[1];   // [200000,128]
    const float* values = (const float*)d_in[2];   // [200000,1]
    float* out = (float*)d_out;
    char* ws = (char*)d_ws;

    const size_t KF_OFF   = 0;
    const size_t QF_OFF   = KF_OFF  + (size_t)NKP * DIM * 2;     // 51,216,384
    const size_t KSQ_OFF  = QF_OFF  + (size_t)N_Q * DIM * 2;     // +262,144
    const size_t QSQ_OFF  = KSQ_OFF + (size_t)NKP * 4;           // +800,256
    const size_t TAU_OFF  = QSQ_OFF + 4096;
    const size_t OVFC_OFF = TAU_OFF + 4096;
    const size_t OVF_OFF  = OVFC_OFF + 4096;
    const size_t CNT2_OFF = OVF_OFF + (size_t)OVFCAP * 8;        // +512 KB
    const size_t CAND2_OFF= CNT2_OFF + (size_t)NSTRIP * N_Q * 4; // +256 KB
    // cand2: 64*1024*64*8 = 33.5 MB. Ds (8 MB) ALIASES the cand2 region:
    // tau_dist writes Ds -> tau_select reads Ds -> filter overwrites cand2 -> select reads cand2.
    // Deterministic per call; no overlap in liveness.

    ushort* Kf  = (ushort*)(ws + KF_OFF);
    ushort* Qf  = (ushort*)(ws + QF_OFF);
    float*  ksq = (float*)(ws + KSQ_OFF);
    float*  qsq = (float*)(ws + QSQ_OFF);
    float*  tau = (float*)(ws + TAU_OFF);
    unsigned int* ovf_cnt = (unsigned int*)(ws + OVFC_OFF);
    uint2*  ovf  = (uint2*)(ws + OVF_OFF);
    unsigned int* cnt2 = (unsigned int*)(ws + CNT2_OFF);
    uint2*  cand2 = (uint2*)(ws + CAND2_OFF);
    float*  Ds   = (float*)(ws + CAND2_OFF);

    const int PREP_BLOCKS = (int)((NKP / 16 + N_Q / 16 + 3) / 4);   // 3142

    hipLaunchKernelGGL(prep_kernel, dim3(PREP_BLOCKS), dim3(256), 0, stream,
                       qry, keys, Kf, Qf, ksq, qsq, ovf_cnt);
    hipLaunchKernelGGL(tau_dist_kernel, dim3(8 * NSTILE), dim3(256), 0, stream,
                       Qf, Kf, ksq, qsq, Ds);
    hipLaunchKernelGGL(tau_select_kernel, dim3(N_Q / 4), dim3(256), 0, stream,
                       Ds, tau, SAMPLE_RANK);
    hipLaunchKernelGGL(mfma_filter_kernel, dim3(8 * NSTRIP), dim3(256), 0, stream,
                       Qf, Kf, ksq, qsq, tau, cand2, cnt2, ovf, ovf_cnt);
    hipLaunchKernelGGL(select_kernel, dim3(N_Q), dim3(256), 0, stream,
                       cand2, cnt2, ovf, ovf_cnt, keys, qry, ksq, qsq, values, out);
}